// Round 1
// baseline (566.008 us; speedup 1.0000x reference)
//
#include <hip/hip_runtime.h>
#include <hip/hip_bf16.h>
#include <math.h>

#define NN    65536
#define EE    524288
#define BBG   64
#define PERG  1024
#define KKEEP 820
#define FF    128

// ---------------- edge aggregation: agg[dst] += x[src], cnt[dst] += 1 ----------------
__global__ __launch_bounds__(256) void k_agg(const float* __restrict__ x,
                                             const int* __restrict__ ei,
                                             float* __restrict__ agg,
                                             float* __restrict__ cnt) {
    int gw   = (blockIdx.x * 256 + threadIdx.x) >> 6;   // global wave id
    int lane = threadIdx.x & 63;
    int nw   = (gridDim.x * 256) >> 6;
    for (int e = gw; e < EE; e += nw) {
        int s = ei[e];
        int d = ei[EE + e];
        float v0 = x[(size_t)s * FF + lane];
        float v1 = x[(size_t)s * FF + 64 + lane];
        atomicAdd(&agg[(size_t)d * FF + lane], v0);
        atomicAdd(&agg[(size_t)d * FF + 64 + lane], v1);
        if (lane == 0) atomicAdd(&cnt[d], 1.0f);
    }
}

__global__ __launch_bounds__(256) void k_invc(const float* __restrict__ cnt,
                                              float* __restrict__ invc) {
    int i = blockIdx.x * 256 + threadIdx.x;
    if (i < NN) invc[i] = 1.0f / fmaxf(cnt[i], 1.0f);
}

// ---------------- h = (agg*invc) @ Wl^T + x @ Wr^T + bl ----------------
// block: 128 nodes x 128 outputs, 256 threads, per-thread 8x8
__global__ __launch_bounds__(256) void k_gemm(const float* __restrict__ agg,
                                              const float* __restrict__ x,
                                              const float* __restrict__ invc,
                                              const float* __restrict__ Wl,
                                              const float* __restrict__ Wr,
                                              const float* __restrict__ bl,
                                              float* __restrict__ h) {
    __shared__ float As[128][33];
    __shared__ float Ws[32][132];
    const int tid  = threadIdx.x;
    const int n0   = blockIdx.x * 128;
    const int tx   = tid & 15;    // output block: o0 = tx*8
    const int ty   = tid >> 4;    // node block:   n  = ty*8 + i
    const int lane = tid & 31;
    const int rw   = tid >> 5;

    float acc[8][8];
#pragma unroll
    for (int i = 0; i < 8; ++i)
#pragma unroll
        for (int j = 0; j < 8; ++j) acc[i][j] = 0.f;

    for (int seg = 0; seg < 2; ++seg) {
        const float* __restrict__ A = seg ? x : agg;
        const float* __restrict__ W = seg ? Wr : Wl;
        for (int c = 0; c < 4; ++c) {
            const int k0 = c * 32;
            __syncthreads();
#pragma unroll
            for (int i = 0; i < 16; ++i) {
                int r = rw + i * 8;
                float v = A[(size_t)(n0 + r) * FF + k0 + lane];
                if (seg == 0) v *= invc[n0 + r];
                As[r][lane] = v;
            }
#pragma unroll
            for (int i = 0; i < 16; ++i) {
                int o = rw + i * 8;
                Ws[lane][o] = W[o * FF + k0 + lane];
            }
            __syncthreads();
#pragma unroll
            for (int kk = 0; kk < 32; ++kk) {
                float a[8];
#pragma unroll
                for (int i = 0; i < 8; ++i) a[i] = As[ty * 8 + i][kk];
                float4 w0 = *(const float4*)&Ws[kk][tx * 8];
                float4 w1 = *(const float4*)&Ws[kk][tx * 8 + 4];
                float wv[8] = {w0.x, w0.y, w0.z, w0.w, w1.x, w1.y, w1.z, w1.w};
#pragma unroll
                for (int i = 0; i < 8; ++i)
#pragma unroll
                    for (int j = 0; j < 8; ++j)
                        acc[i][j] = fmaf(a[i], wv[j], acc[i][j]);
            }
        }
    }
#pragma unroll
    for (int i = 0; i < 8; ++i) {
        int n = n0 + ty * 8 + i;
        float4 o0, o1;
        o0.x = acc[i][0] + bl[tx * 8 + 0];
        o0.y = acc[i][1] + bl[tx * 8 + 1];
        o0.z = acc[i][2] + bl[tx * 8 + 2];
        o0.w = acc[i][3] + bl[tx * 8 + 3];
        o1.x = acc[i][4] + bl[tx * 8 + 4];
        o1.y = acc[i][5] + bl[tx * 8 + 5];
        o1.z = acc[i][6] + bl[tx * 8 + 6];
        o1.w = acc[i][7] + bl[tx * 8 + 7];
        *(float4*)&h[(size_t)n * FF + tx * 8]     = o0;
        *(float4*)&h[(size_t)n * FF + tx * 8 + 4] = o1;
    }
}

// ---------------- BN stats: per-feature sum & sumsq ----------------
__global__ __launch_bounds__(256) void k_stats(const float* __restrict__ h,
                                               float* __restrict__ stats) {
    int tid = threadIdx.x;
    int f   = tid & 127;
    int p   = tid >> 7;
    int r0  = blockIdx.x * 64;
    float s = 0.f, s2 = 0.f;
    for (int i = p; i < 64; i += 2) {
        float v = h[(size_t)(r0 + i) * FF + f];
        s += v;
        s2 += v * v;
    }
    __shared__ float sh[256], sh2[256];
    sh[tid]  = s;
    sh2[tid] = s2;
    __syncthreads();
    if (p == 0) {
        atomicAdd(&stats[f],       sh[tid] + sh[tid + 128]);
        atomicAdd(&stats[128 + f], sh2[tid] + sh2[tid + 128]);
    }
}

// stats: [0:128) sum, [128:256) sumsq, [256:384) scale, [384:512) shift, [512:640) attn/||attn||
__global__ __launch_bounds__(128) void k_bnparam(const float* __restrict__ gamma,
                                                 const float* __restrict__ beta,
                                                 const float* __restrict__ attn,
                                                 float* __restrict__ stats) {
    int f = threadIdx.x;
    float mean = stats[f] / (float)NN;
    float var  = stats[128 + f] / (float)NN - mean * mean;
    float inv  = 1.0f / sqrtf(var + 1e-5f);
    float sc   = gamma[f] * inv;
    stats[256 + f] = sc;
    stats[384 + f] = beta[f] - mean * sc;
    __shared__ float sa[128];
    float a = attn[f];
    sa[f] = a * a;
    __syncthreads();
    for (int s = 64; s > 0; s >>= 1) {
        if (f < s) sa[f] += sa[f + s];
        __syncthreads();
    }
    stats[512 + f] = a / sqrtf(sa[0]);
}

// ---------------- normalize + relu (in place) + score ----------------
__global__ __launch_bounds__(256) void k_norm(float* __restrict__ h,
                                              const float* __restrict__ stats,
                                              float* __restrict__ score) {
    int node = (blockIdx.x * 256 + threadIdx.x) >> 6;
    int lane = threadIdx.x & 63;
    float sc0 = stats[256 + lane],      sh0 = stats[384 + lane];
    float sc1 = stats[256 + 64 + lane], sh1 = stats[384 + 64 + lane];
    float a0  = stats[512 + lane],      a1  = stats[512 + 64 + lane];
    size_t base = (size_t)node * FF;
    float v0 = fmaxf(h[base + lane] * sc0 + sh0, 0.f);
    float v1 = fmaxf(h[base + 64 + lane] * sc1 + sh1, 0.f);
    h[base + lane]      = v0;
    h[base + 64 + lane] = v1;
    float s = v0 * a0 + v1 * a1;
#pragma unroll
    for (int off = 32; off > 0; off >>= 1) s += __shfl_down(s, off);
    if (lane == 0) score[node] = s;
}

// ---------------- per-graph bitonic sort (desc, stable) + perm/node_map ----------------
__global__ __launch_bounds__(1024) void k_topk(const float* __restrict__ score,
                                               int* __restrict__ nmap,
                                               int* __restrict__ plist,
                                               float* __restrict__ out_batch) {
    __shared__ unsigned long long keys[PERG];
    int b = blockIdx.x;
    int t = threadIdx.x;
    float s = score[b * PERG + t];
    unsigned u = __float_as_uint(s);
    u = (u & 0x80000000u) ? ~u : (u | 0x80000000u);
    keys[t] = ((unsigned long long)u << 10) | (unsigned long long)(1023 - t);
    __syncthreads();
    for (int k = 2; k <= PERG; k <<= 1) {
        for (int j = k >> 1; j > 0; j >>= 1) {
            int l = t ^ j;
            if (l > t) {
                bool asc = ((t & k) != 0);   // overall descending
                unsigned long long a = keys[t], c = keys[l];
                if ((a > c) == asc) { keys[t] = c; keys[l] = a; }
            }
            __syncthreads();
        }
    }
    if (t < KKEEP) {
        int idx = 1023 - (int)(keys[t] & 1023ull);
        int g   = b * PERG + idx;
        int nid = b * KKEEP + t;
        plist[nid]     = g;
        nmap[g]        = nid;
        out_batch[nid] = (float)b;
    }
}

// ---------------- hp = h[perm] * tanh(score[perm]) ----------------
__global__ __launch_bounds__(256) void k_hp(const float* __restrict__ h,
                                            const float* __restrict__ score,
                                            const int* __restrict__ plist,
                                            float* __restrict__ out_hp) {
    int row  = blockIdx.x * 4 + (threadIdx.x >> 6);
    int lane = threadIdx.x & 63;
    int g    = plist[row];
    float tt = tanhf(score[g]);
    float2 v = *(const float2*)(h + (size_t)g * FF + lane * 2);
    v.x *= tt;
    v.y *= tt;
    *(float2*)(out_hp + (size_t)row * FF + lane * 2) = v;
}

// ---------------- per-graph sum & max pooling ----------------
__global__ __launch_bounds__(256) void k_flat(const float* __restrict__ hp,
                                              float* __restrict__ out_flat) {
    int b   = blockIdx.x;
    int tid = threadIdx.x;
    int f   = tid & 127;
    int p   = tid >> 7;
    float s = 0.f, m = -INFINITY;
    const float* base = hp + (size_t)b * KKEEP * FF;
    for (int r = p; r < KKEEP; r += 2) {
        float v = base[r * FF + f];
        s += v;
        m = fmaxf(m, v);
    }
    __shared__ float ss[256], mm[256];
    ss[tid] = s;
    mm[tid] = m;
    __syncthreads();
    if (p == 0) {
        out_flat[b * 256 + f]       = ss[tid] + ss[tid + 128];
        out_flat[b * 256 + 128 + f] = fmaxf(mm[tid], mm[tid + 128]);
    }
}

// ---------------- edge reindex ----------------
__global__ __launch_bounds__(256) void k_edge(const int* __restrict__ ei,
                                              const int* __restrict__ nmap,
                                              float* __restrict__ out_edge) {
    int e = blockIdx.x * 256 + threadIdx.x;
    if (e >= EE) return;
    int s  = ei[e];
    int d  = ei[EE + e];
    int ns = nmap[s];
    int nd = nmap[d];
    bool keep = (ns >= 0) && (nd >= 0);
    out_edge[e]      = keep ? (float)ns : -1.0f;
    out_edge[EE + e] = keep ? (float)nd : -1.0f;
}

extern "C" void kernel_launch(void* const* d_in, const int* in_sizes, int n_in,
                              void* d_out, int out_size, void* d_ws, size_t ws_size,
                              hipStream_t stream) {
    const float* x    = (const float*)d_in[0];
    const int*   ei   = (const int*)d_in[1];
    const float* Wl   = (const float*)d_in[3];
    const float* bl   = (const float*)d_in[4];
    const float* Wr   = (const float*)d_in[5];
    const float* gam  = (const float*)d_in[6];
    const float* bet  = (const float*)d_in[7];
    const float* attn = (const float*)d_in[8];

    // workspace layout
    float* agg   = (float*)d_ws;                 // NN*FF
    float* h     = agg + (size_t)NN * FF;        // NN*FF
    float* cnt   = h + (size_t)NN * FF;          // NN
    float* invc  = cnt + NN;                     // NN
    float* score = invc + NN;                    // NN
    int*   nmap  = (int*)(score + NN);           // NN
    int*   plist = nmap + NN;                    // BBG*KKEEP
    float* stats = (float*)(plist + BBG * KKEEP);// 5*128

    // output layout (all float32)
    float* out       = (float*)d_out;
    float* out_hp    = out;                          // 52480*128
    float* out_flat  = out_hp + (size_t)BBG * KKEEP * FF;  // 64*256
    float* out_edge  = out_flat + BBG * 256;         // 2*EE
    float* out_batch = out_edge + 2 * EE;            // 52480

    hipMemsetAsync(agg, 0, (size_t)NN * FF * sizeof(float), stream);
    hipMemsetAsync(cnt, 0, (size_t)NN * sizeof(float), stream);
    hipMemsetAsync(stats, 0, 5 * 128 * sizeof(float), stream);
    hipMemsetAsync(nmap, 0xFF, (size_t)NN * sizeof(int), stream);

    k_agg<<<2048, 256, 0, stream>>>(x, ei, agg, cnt);
    k_invc<<<NN / 256, 256, 0, stream>>>(cnt, invc);
    k_gemm<<<NN / 128, 256, 0, stream>>>(agg, x, invc, Wl, Wr, bl, h);
    k_stats<<<NN / 64, 256, 0, stream>>>(h, stats);
    k_bnparam<<<1, 128, 0, stream>>>(gam, bet, attn, stats);
    k_norm<<<NN / 4, 256, 0, stream>>>(h, stats, score);
    k_topk<<<BBG, 1024, 0, stream>>>(score, nmap, plist, out_batch);
    k_hp<<<(BBG * KKEEP) / 4, 256, 0, stream>>>(h, score, plist, out_hp);
    k_flat<<<BBG, 256, 0, stream>>>(out_hp, out_flat);
    k_edge<<<EE / 256, 256, 0, stream>>>(ei, nmap, out_edge);
}

// Round 2
// 345.702 us; speedup vs baseline: 1.6373x; 1.6373x over previous
//
#include <hip/hip_runtime.h>
#include <hip/hip_bf16.h>
#include <math.h>

#define NN    65536
#define EE    524288
#define BBG   64
#define PERG  1024
#define KKEEP 820
#define FF    128

// ---------------- degree histogram ----------------
__global__ __launch_bounds__(256) void k_deg(const int* __restrict__ ei,
                                             int* __restrict__ deg) {
    int e = blockIdx.x * 256 + threadIdx.x;
    if (e < EE) atomicAdd(&deg[ei[EE + e]], 1);
}

// ---------------- 3-stage exclusive scan of deg -> starts ----------------
__global__ __launch_bounds__(256) void k_scan1(const int* __restrict__ deg,
                                               int* __restrict__ spart,
                                               int* __restrict__ bsum) {
    int t = threadIdx.x;
    int i = blockIdx.x * 256 + t;
    __shared__ int sh[256];
    int v = deg[i];
    sh[t] = v;
    __syncthreads();
    for (int o = 1; o < 256; o <<= 1) {
        int u = (t >= o) ? sh[t - o] : 0;
        __syncthreads();
        sh[t] += u;
        __syncthreads();
    }
    spart[i] = sh[t];                       // inclusive within block
    if (t == 255) bsum[blockIdx.x] = sh[255];
}

__global__ __launch_bounds__(256) void k_scan2(const int* __restrict__ bsum,
                                               int* __restrict__ boff) {
    int t = threadIdx.x;
    __shared__ int sh[256];
    int v = bsum[t];
    sh[t] = v;
    __syncthreads();
    for (int o = 1; o < 256; o <<= 1) {
        int u = (t >= o) ? sh[t - o] : 0;
        __syncthreads();
        sh[t] += u;
        __syncthreads();
    }
    boff[t] = sh[t] - v;                    // exclusive block offsets
}

__global__ __launch_bounds__(256) void k_scan3(const int* __restrict__ deg,
                                               const int* __restrict__ spart,
                                               const int* __restrict__ boff,
                                               int* __restrict__ starts,
                                               int* __restrict__ cursor) {
    int i = blockIdx.x * 256 + threadIdx.x;
    int st = spart[i] - deg[i] + boff[i >> 8];   // global exclusive prefix
    starts[i] = st;
    cursor[i] = st;
    if (i == 0) starts[NN] = EE;
}

// ---------------- scatter edges into CSR ----------------
__global__ __launch_bounds__(256) void k_scatter(const int* __restrict__ ei,
                                                 int* __restrict__ cursor,
                                                 int* __restrict__ ssrc) {
    int e = blockIdx.x * 256 + threadIdx.x;
    if (e >= EE) return;
    int s = ei[e];
    int d = ei[EE + e];
    int pos = atomicAdd(&cursor[d], 1);
    ssrc[pos] = s;
}

// ---------------- per-node mean gather: one wave per node ----------------
__global__ __launch_bounds__(256) void k_gather(const float* __restrict__ x,
                                                const int* __restrict__ ssrc,
                                                const int* __restrict__ starts,
                                                float* __restrict__ mean) {
    int n    = blockIdx.x * 4 + (threadIdx.x >> 6);
    int lane = threadIdx.x & 63;
    int d0 = starts[n], d1 = starts[n + 1];
    float2 acc = make_float2(0.f, 0.f);
    int e = d0;
    for (; e + 1 < d1; e += 2) {
        int s0 = ssrc[e], s1 = ssrc[e + 1];
        float2 v0 = *(const float2*)(x + (size_t)s0 * FF + lane * 2);
        float2 v1 = *(const float2*)(x + (size_t)s1 * FF + lane * 2);
        acc.x += v0.x + v1.x;
        acc.y += v0.y + v1.y;
    }
    if (e < d1) {
        int s0 = ssrc[e];
        float2 v0 = *(const float2*)(x + (size_t)s0 * FF + lane * 2);
        acc.x += v0.x;
        acc.y += v0.y;
    }
    float inv = 1.0f / fmaxf((float)(d1 - d0), 1.0f);
    acc.x *= inv;
    acc.y *= inv;
    *(float2*)(mean + (size_t)n * FF + lane * 2) = acc;
}

// ---------------- h = mean @ Wl^T + x @ Wr^T + bl   (+fused BN stats) ----------------
__global__ __launch_bounds__(256) void k_gemm(const float* __restrict__ mean,
                                              const float* __restrict__ x,
                                              const float* __restrict__ Wl,
                                              const float* __restrict__ Wr,
                                              const float* __restrict__ bl,
                                              float* __restrict__ h,
                                              float* __restrict__ stats) {
    __shared__ float As[128][33];
    __shared__ float Ws[32][132];
    const int tid  = threadIdx.x;
    const int n0   = blockIdx.x * 128;
    const int tx   = tid & 15;    // output block: o0 = tx*8
    const int ty   = tid >> 4;    // node block:   n  = ty*8 + i
    const int lane = tid & 31;
    const int rw   = tid >> 5;

    float acc[8][8];
#pragma unroll
    for (int i = 0; i < 8; ++i)
#pragma unroll
        for (int j = 0; j < 8; ++j) acc[i][j] = 0.f;

    for (int seg = 0; seg < 2; ++seg) {
        const float* __restrict__ A = seg ? x : mean;
        const float* __restrict__ W = seg ? Wr : Wl;
        for (int c = 0; c < 4; ++c) {
            const int k0 = c * 32;
            __syncthreads();
#pragma unroll
            for (int i = 0; i < 16; ++i) {
                int r = rw + i * 8;
                As[r][lane] = A[(size_t)(n0 + r) * FF + k0 + lane];
            }
#pragma unroll
            for (int i = 0; i < 16; ++i) {
                int o = rw + i * 8;
                Ws[lane][o] = W[o * FF + k0 + lane];
            }
            __syncthreads();
#pragma unroll
            for (int kk = 0; kk < 32; ++kk) {
                float a[8];
#pragma unroll
                for (int i = 0; i < 8; ++i) a[i] = As[ty * 8 + i][kk];
                float4 w0 = *(const float4*)&Ws[kk][tx * 8];
                float4 w1 = *(const float4*)&Ws[kk][tx * 8 + 4];
                float wv[8] = {w0.x, w0.y, w0.z, w0.w, w1.x, w1.y, w1.z, w1.w};
#pragma unroll
                for (int i = 0; i < 8; ++i)
#pragma unroll
                    for (int j = 0; j < 8; ++j)
                        acc[i][j] = fmaf(a[i], wv[j], acc[i][j]);
            }
        }
    }

    float bj[8];
#pragma unroll
    for (int j = 0; j < 8; ++j) bj[j] = bl[tx * 8 + j];

    float s1[8], s2[8];
#pragma unroll
    for (int j = 0; j < 8; ++j) { s1[j] = 0.f; s2[j] = 0.f; }

#pragma unroll
    for (int i = 0; i < 8; ++i) {
        int n = n0 + ty * 8 + i;
        float v[8];
#pragma unroll
        for (int j = 0; j < 8; ++j) {
            v[j] = acc[i][j] + bj[j];
            s1[j] += v[j];
            s2[j] += v[j] * v[j];
        }
        *(float4*)&h[(size_t)n * FF + tx * 8]     = make_float4(v[0], v[1], v[2], v[3]);
        *(float4*)&h[(size_t)n * FF + tx * 8 + 4] = make_float4(v[4], v[5], v[6], v[7]);
    }

    // fused BN stats: reduce the 16 ty-groups per (feature) then atomics
    __syncthreads();                       // done reading As/Ws
    float* sbuf  = &As[0][0];              // 2048 floats needed
    float* s2buf = &Ws[0][0];
#pragma unroll
    for (int j = 0; j < 8; ++j) {
        sbuf[(tx * 8 + j) * 16 + ty]  = s1[j];
        s2buf[(tx * 8 + j) * 16 + ty] = s2[j];
    }
    __syncthreads();
    if (tid < 128) {
        float a = 0.f, b = 0.f;
#pragma unroll
        for (int t = 0; t < 16; ++t) {
            a += sbuf[tid * 16 + t];
            b += s2buf[tid * 16 + t];
        }
        atomicAdd(&stats[tid], a);
        atomicAdd(&stats[128 + tid], b);
    }
}

// stats: [0:128) sum, [128:256) sumsq, [256:384) scale, [384:512) shift, [512:640) attn/||attn||
__global__ __launch_bounds__(128) void k_bnparam(const float* __restrict__ gamma,
                                                 const float* __restrict__ beta,
                                                 const float* __restrict__ attn,
                                                 float* __restrict__ stats) {
    int f = threadIdx.x;
    float mean = stats[f] / (float)NN;
    float var  = stats[128 + f] / (float)NN - mean * mean;
    float inv  = 1.0f / sqrtf(var + 1e-5f);
    float sc   = gamma[f] * inv;
    stats[256 + f] = sc;
    stats[384 + f] = beta[f] - mean * sc;
    __shared__ float sa[128];
    float a = attn[f];
    sa[f] = a * a;
    __syncthreads();
    for (int s = 64; s > 0; s >>= 1) {
        if (f < s) sa[f] += sa[f + s];
        __syncthreads();
    }
    stats[512 + f] = a / sqrtf(sa[0]);
}

// ---------------- normalize + relu (in place) + score ----------------
__global__ __launch_bounds__(256) void k_norm(float* __restrict__ h,
                                              const float* __restrict__ stats,
                                              float* __restrict__ score) {
    int node = (blockIdx.x * 256 + threadIdx.x) >> 6;
    int lane = threadIdx.x & 63;
    float sc0 = stats[256 + lane],      sh0 = stats[384 + lane];
    float sc1 = stats[256 + 64 + lane], sh1 = stats[384 + 64 + lane];
    float a0  = stats[512 + lane],      a1  = stats[512 + 64 + lane];
    size_t base = (size_t)node * FF;
    float v0 = fmaxf(h[base + lane] * sc0 + sh0, 0.f);
    float v1 = fmaxf(h[base + 64 + lane] * sc1 + sh1, 0.f);
    h[base + lane]      = v0;
    h[base + 64 + lane] = v1;
    float s = v0 * a0 + v1 * a1;
#pragma unroll
    for (int off = 32; off > 0; off >>= 1) s += __shfl_down(s, off);
    if (lane == 0) score[node] = s;
}

// ---------------- per-graph bitonic sort (desc, stable) + perm/node_map ----------------
__global__ __launch_bounds__(1024) void k_topk(const float* __restrict__ score,
                                               int* __restrict__ nmap,
                                               int* __restrict__ plist,
                                               float* __restrict__ out_batch) {
    __shared__ unsigned long long keys[PERG];
    int b = blockIdx.x;
    int t = threadIdx.x;
    float s = score[b * PERG + t];
    unsigned u = __float_as_uint(s);
    u = (u & 0x80000000u) ? ~u : (u | 0x80000000u);
    keys[t] = ((unsigned long long)u << 10) | (unsigned long long)(1023 - t);
    __syncthreads();
    for (int k = 2; k <= PERG; k <<= 1) {
        for (int j = k >> 1; j > 0; j >>= 1) {
            int l = t ^ j;
            if (l > t) {
                bool asc = ((t & k) != 0);   // overall descending
                unsigned long long a = keys[t], c = keys[l];
                if ((a > c) == asc) { keys[t] = c; keys[l] = a; }
            }
            __syncthreads();
        }
    }
    if (t < KKEEP) {
        int idx = 1023 - (int)(keys[t] & 1023ull);
        int g   = b * PERG + idx;
        int nid = b * KKEEP + t;
        plist[nid]     = g;
        nmap[g]        = nid;
        out_batch[nid] = (float)b;
    }
}

// ---------------- hp = h[perm] * tanh(score[perm]) ----------------
__global__ __launch_bounds__(256) void k_hp(const float* __restrict__ h,
                                            const float* __restrict__ score,
                                            const int* __restrict__ plist,
                                            float* __restrict__ out_hp) {
    int row  = blockIdx.x * 4 + (threadIdx.x >> 6);
    int lane = threadIdx.x & 63;
    int g    = plist[row];
    float tt = tanhf(score[g]);
    float2 v = *(const float2*)(h + (size_t)g * FF + lane * 2);
    v.x *= tt;
    v.y *= tt;
    *(float2*)(out_hp + (size_t)row * FF + lane * 2) = v;
}

// ---------------- per-graph sum & max pooling ----------------
__global__ __launch_bounds__(256) void k_flat(const float* __restrict__ hp,
                                              float* __restrict__ out_flat) {
    int b   = blockIdx.x;
    int tid = threadIdx.x;
    int f   = tid & 127;
    int p   = tid >> 7;
    float s = 0.f, m = -INFINITY;
    const float* base = hp + (size_t)b * KKEEP * FF;
    for (int r = p; r < KKEEP; r += 2) {
        float v = base[r * FF + f];
        s += v;
        m = fmaxf(m, v);
    }
    __shared__ float ss[256], mm[256];
    ss[tid] = s;
    mm[tid] = m;
    __syncthreads();
    if (p == 0) {
        out_flat[b * 256 + f]       = ss[tid] + ss[tid + 128];
        out_flat[b * 256 + 128 + f] = fmaxf(mm[tid], mm[tid + 128]);
    }
}

// ---------------- edge reindex ----------------
__global__ __launch_bounds__(256) void k_edge(const int* __restrict__ ei,
                                              const int* __restrict__ nmap,
                                              float* __restrict__ out_edge) {
    int e = blockIdx.x * 256 + threadIdx.x;
    if (e >= EE) return;
    int s  = ei[e];
    int d  = ei[EE + e];
    int ns = nmap[s];
    int nd = nmap[d];
    bool keep = (ns >= 0) && (nd >= 0);
    out_edge[e]      = keep ? (float)ns : -1.0f;
    out_edge[EE + e] = keep ? (float)nd : -1.0f;
}

extern "C" void kernel_launch(void* const* d_in, const int* in_sizes, int n_in,
                              void* d_out, int out_size, void* d_ws, size_t ws_size,
                              hipStream_t stream) {
    const float* x    = (const float*)d_in[0];
    const int*   ei   = (const int*)d_in[1];
    const float* Wl   = (const float*)d_in[3];
    const float* bl   = (const float*)d_in[4];
    const float* Wr   = (const float*)d_in[5];
    const float* gam  = (const float*)d_in[6];
    const float* bet  = (const float*)d_in[7];
    const float* attn = (const float*)d_in[8];

    // workspace layout
    float* mean  = (float*)d_ws;                 // NN*FF
    float* h     = mean + (size_t)NN * FF;       // NN*FF
    float* score = h + (size_t)NN * FF;          // NN
    int*   nmap  = (int*)(score + NN);           // NN
    int*   plist = nmap + NN;                    // BBG*KKEEP
    float* stats = (float*)(plist + BBG * KKEEP);// 5*128

    // CSR scratch aliased into h (dead until k_gemm writes it)
    int* deg    = (int*)h;          // NN
    int* spart  = deg + NN;         // NN
    int* starts = spart + NN;       // NN+1
    int* cursor = starts + NN + 1;  // NN
    int* ssrc   = cursor + NN;      // EE
    int* bsum   = ssrc + EE;        // 256
    int* boff   = bsum + 256;       // 256

    // output layout (all float32)
    float* out       = (float*)d_out;
    float* out_hp    = out;                                // 52480*128
    float* out_flat  = out_hp + (size_t)BBG * KKEEP * FF;  // 64*256
    float* out_edge  = out_flat + BBG * 256;               // 2*EE
    float* out_batch = out_edge + 2 * EE;                  // 52480

    hipMemsetAsync(deg, 0, (size_t)NN * sizeof(int), stream);
    hipMemsetAsync(stats, 0, 5 * 128 * sizeof(float), stream);
    hipMemsetAsync(nmap, 0xFF, (size_t)NN * sizeof(int), stream);

    k_deg<<<EE / 256, 256, 0, stream>>>(ei, deg);
    k_scan1<<<256, 256, 0, stream>>>(deg, spart, bsum);
    k_scan2<<<1, 256, 0, stream>>>(bsum, boff);
    k_scan3<<<256, 256, 0, stream>>>(deg, spart, boff, starts, cursor);
    k_scatter<<<EE / 256, 256, 0, stream>>>(ei, cursor, ssrc);
    k_gather<<<NN / 4, 256, 0, stream>>>(x, ssrc, starts, mean);
    k_gemm<<<NN / 128, 256, 0, stream>>>(mean, x, Wl, Wr, bl, h, stats);
    k_bnparam<<<1, 128, 0, stream>>>(gam, bet, attn, stats);
    k_norm<<<NN / 4, 256, 0, stream>>>(h, stats, score);
    k_topk<<<BBG, 1024, 0, stream>>>(score, nmap, plist, out_batch);
    k_hp<<<(BBG * KKEEP) / 4, 256, 0, stream>>>(h, score, plist, out_hp);
    k_flat<<<BBG, 256, 0, stream>>>(out_hp, out_flat);
    k_edge<<<EE / 256, 256, 0, stream>>>(ei, nmap, out_edge);
}